// Round 15
// baseline (3532.639 us; speedup 1.0000x reference)
//
#include <hip/hip_runtime.h>

// SignalingModel: X_{t+1} = mml(W @ X_t + X_bias), 60 steps, W 0.24% sparse.
// R12 = R11 + build-time BANK-CONFLICT SCHEDULING of the 14 register slots:
//  - per sim-wave greedy: each slot, each lane picks its remaining edge with
//    least-loaded bank-pair (src%16) -> flattens 6-8-way hotspots to ~4-way
//    (absorbed by b64's 4-cycle pump).
//  - dead slots read the SAME address as a real lane in that slot ->
//    broadcast, zero bank cost (was: pile-up on offset 0 / wasted slot).
//  - slot reorder changes only intra-node fp sum order (~1e-6 << 1.77e-2 thr).
//  - inner loop on ext_vector float2 to encourage v_pk_fma_f32.
// Lessons: LDS effective cycles (latency+conflict+barrier) is the serial
// resource; per-sample LDS bytes invariant in SPB; random b64 conflict-
// tolerant (R10/R11); register edges need compile-time indexing (R9).

#define NN 2048
#define STEPS 60
#define LEAKV 0.01f
#define EMAX 10240
#define TPB 1024
#define SPB 2
#define NB 64
#define EPT 14            // register slots per thread (zigzag pair-sum ~p99)
#define BUF1 16384        // byte offset of second state buffer (NN*8)

typedef float vf2 __attribute__((ext_vector_type(2)));

__device__ __forceinline__ float mml_f(float x) {
  if (x < 0.0f)      return LEAKV * x;
  else if (x < 0.5f) return x;
  else               return 1.0f - 0.25f / x;
}

// --- build pipeline -------------------------------------------------------

__global__ __launch_bounds__(64) void count_row(const float* __restrict__ W,
                                                int* __restrict__ cnt) {
  const int n = blockIdx.x, lane = threadIdx.x;
  int c = 0;
  for (int c0 = 0; c0 < NN; c0 += 64) {
    float w = W[n * NN + c0 + lane];
    c += __popcll(__ballot(w != 0.0f));
  }
  if (lane == 0) cnt[n] = c;
}

__global__ __launch_bounds__(1024) void scan2048(const int* __restrict__ cnt,
                                                 int* __restrict__ base) {
  __shared__ int sb[2][NN];
  const int t = threadIdx.x;
  sb[0][t] = cnt[t];
  sb[0][t + 1024] = cnt[t + 1024];
  __syncthreads();
  int p = 0;
  for (int off = 1; off < NN; off <<= 1) {
    int i0 = t, i1 = t + 1024;
    sb[p ^ 1][i0] = sb[p][i0] + (i0 >= off ? sb[p][i0 - off] : 0);
    sb[p ^ 1][i1] = sb[p][i1] + (i1 >= off ? sb[p][i1 - off] : 0);
    __syncthreads();
    p ^= 1;
  }
  base[t] = sb[p][t] - cnt[t];
  base[t + 1024] = sb[p][t + 1024] - cnt[t + 1024];
  if (t == 1023) base[NN] = sb[p][NN - 1];
}

__global__ __launch_bounds__(64) void fill_edges(const float* __restrict__ W,
                                                 const int* __restrict__ base,
                                                 uint2* __restrict__ pg) {
  const int n = blockIdx.x, lane = threadIdx.x;
  const int b = base[n];
  int off = 0;
  for (int c0 = 0; c0 < NN; c0 += 64) {
    float w = W[n * NN + c0 + lane];
    unsigned long long m = __ballot(w != 0.0f);
    if (w != 0.0f) {
      int e = b + off + __popcll(m & ((1ull << lane) - 1ull));
      pg[e] = make_uint2(__float_as_uint(w), (unsigned)(c0 + lane));
    }
    off += __popcll(m);
  }
}

// degree counting-sort: perm[rank]=node, ascending. Unstable within bucket --
// output-invariant (per-node edges keep their identity wherever they land).
__global__ __launch_bounds__(1024) void sortnodes(const int* __restrict__ cnt,
                                                  int* __restrict__ perm) {
  __shared__ int bases[NB];
  const int t = threadIdx.x;
  if (t < NB) bases[t] = 0;
  __syncthreads();
  int d0 = min(cnt[t], NB - 1);
  int d1 = min(cnt[t + 1024], NB - 1);
  atomicAdd(&bases[d0], 1);
  atomicAdd(&bases[d1], 1);
  __syncthreads();
  if (t == 0) {
    int acc = 0;
    for (int i = 0; i < NB; ++i) { int h = bases[i]; bases[i] = acc; acc += h; }
  }
  __syncthreads();
  perm[atomicAdd(&bases[d0], 1)] = t;
  perm[atomicAdd(&bases[d1], 1)] = t + 1024;
}

// zigzag pair + thread-contiguous edge re-layout (CSR order preserved).
__global__ __launch_bounds__(1024) void pair_layout(const int* __restrict__ cnt,
                                                    const int* __restrict__ base,
                                                    const uint2* __restrict__ pg,
                                                    const int* __restrict__ perm,
                                                    uint2* __restrict__ e2,
                                                    int* __restrict__ tb,
                                                    int* __restrict__ tmid,
                                                    int* __restrict__ pa,
                                                    int* __restrict__ pb) {
  __shared__ int sc[2][1024];
  const int t = threadIdx.x;
  const int nA = perm[t], nB = perm[2047 - t];
  const int dA = cnt[nA], dB = cnt[nB];
  sc[0][t] = dA + dB;
  __syncthreads();
  int p = 0;
  for (int off = 1; off < 1024; off <<= 1) {
    sc[p ^ 1][t] = sc[p][t] + (t >= off ? sc[p][t - off] : 0);
    __syncthreads();
    p ^= 1;
  }
  const int b = sc[p][t] - (dA + dB);
  tb[t] = b;
  tmid[t] = b + dA;
  pa[t] = nA;
  pb[t] = nB;
  if (t == 1023) tb[1024] = sc[p][t];
  const int bA = base[nA], bB = base[nB];
  for (int k = 0; k < dA; ++k) e2[b + k] = pg[bA + k];
  for (int k = 0; k < dB; ++k) e2[b + dA + k] = pg[bB + k];
}

// node renumbering: thread t's nodes become new-ids {2t, 2t+1}
__global__ __launch_bounds__(1024) void renum(const int* __restrict__ pa,
                                              const int* __restrict__ pb,
                                              int* __restrict__ newid) {
  const int t = threadIdx.x;
  newid[pa[t]] = 2 * t;
  newid[pb[t]] = 2 * t + 1;
}

__global__ __launch_bounds__(256) void remap(uint2* __restrict__ e2,
                                             const int* __restrict__ newid) {
  const int e = blockIdx.x * 256 + threadIdx.x;
  e2[e].y = (unsigned)newid[e2[e].y];
}

// bank-conflict scheduler: one thread per sim-wave. For each slot k, each
// lane greedily takes its remaining edge with least-loaded bank-pair
// (src%16); dead lanes copy a real lane's byte-offset (broadcast = free).
// Output e3[k*1024 + t] = (w_bits, (boff<<1)|isA).
__global__ __launch_bounds__(16) void sched(const uint2* __restrict__ e2,
                                            const int* __restrict__ tb,
                                            const int* __restrict__ tmid,
                                            uint2* __restrict__ e3) {
  const int w = threadIdx.x;               // sim-wave id 0..15
  unsigned short used[64];
  unsigned char deg[64];
  for (int l = 0; l < 64; ++l) {
    const int t = w * 64 + l;
    int d = tb[t + 1] - tb[t];
    deg[l] = (unsigned char)(d > EPT ? EPT : d);
    used[l] = 0;
  }
  for (int k = 0; k < EPT; ++k) {
    int load[16];
    for (int i = 0; i < 16; ++i) load[i] = 0;
    int anyoff = 0;
    for (int l = 0; l < 64; ++l) {
      const int t = w * 64 + l, b0 = tb[t];
      int best = -1, bl = 1 << 30;
      for (int i = 0; i < (int)deg[l]; ++i) {
        if (used[l] & (1u << i)) continue;
        const int bp = (int)(e2[b0 + i].y & 15u);
        if (load[bp] < bl) { bl = load[bp]; best = i; }
      }
      if (best >= 0) {
        used[l] |= (unsigned short)(1u << best);
        const uint2 en = e2[b0 + best];
        const int isA = (b0 + best) < tmid[t] ? 1 : 0;
        const int boff = (int)(en.y * 8u);
        e3[k * 1024 + t] = make_uint2(en.x, (unsigned)((boff << 1) | isA));
        load[en.y & 15u]++;
        anyoff = boff;
      } else {
        e3[k * 1024 + t] = make_uint2(0u, 0x80000000u);   // sentinel
      }
    }
    for (int l = 0; l < 64; ++l) {       // dead lanes: broadcast a real addr
      const int t = w * 64 + l;
      if (e3[k * 1024 + t].y == 0x80000000u)
        e3[k * 1024 + t] = make_uint2(0u, (unsigned)(anyoff << 1));
    }
  }
}

// --- simulation -----------------------------------------------------------
// one block = 2 samples; state float2{s0,s1}[NN] x2 (32 KB static); thread t
// owns new-ids {2t,2t+1}; 14 scheduled edges/thread in registers; paired
// b128 store; ping-pong via compile-time ds offset immediates.
__global__ __launch_bounds__(TPB, 4) void sim(const float* __restrict__ Xfull,
                                              const float* __restrict__ bias,
                                              const uint2* __restrict__ e2,
                                              const uint2* __restrict__ e3,
                                              const int* __restrict__ tb,
                                              const int* __restrict__ tmid,
                                              const int* __restrict__ pa,
                                              const int* __restrict__ pb,
                                              float* __restrict__ out) {
  __shared__ float2 X[2][NN];                     // 32 KB
  char* Xb = (char*)&X[0][0];
  const int t  = (int)threadIdx.x;
  const int s0 = (int)blockIdx.x * SPB;

  const int eA1 = tmid[t], eB1 = tb[t + 1];
  const int spill0 = tb[t] + EPT;
  const int oldA = pa[t], oldB = pb[t];

  // hoist scheduled edges into registers (coalesced slot-major reads).
  float wA[EPT], wB[EPT];
  int boff[EPT];
#pragma unroll
  for (int k = 0; k < EPT; ++k) {
    const uint2 en = e3[k * 1024 + t];
    const float wv = __uint_as_float(en.x);
    const bool isA = (en.y & 1u) != 0u;
    wA[k] = isA ? wv : 0.0f;
    wB[k] = isA ? 0.0f : wv;
    boff[k] = (int)(en.y >> 1);
  }

  const vf2 xbA = {Xfull[(size_t)s0 * NN + oldA] + bias[oldA],
                   Xfull[(size_t)(s0 + 1) * NN + oldA] + bias[oldA]};
  const vf2 xbB = {Xfull[(size_t)s0 * NN + oldB] + bias[oldB],
                   Xfull[(size_t)(s0 + 1) * NN + oldB] + bias[oldB]};
  const int wr = t * 16;

  // X1 = mml(W@0 + xb) = mml(xb) into buffer 0
  *(float4*)(Xb + wr) = make_float4(mml_f(xbA.x), mml_f(xbA.y),
                                    mml_f(xbB.x), mml_f(xbB.y));
  __syncthreads();

  vf2 yA, yB;

#define STEP(SRCOFF, DSTOFF)                                                 \
  {                                                                          \
    vf2 aA = xbA, aB = xbB;                                                  \
    _Pragma("unroll")                                                        \
    for (int k = 0; k < EPT; ++k) {                                          \
      const vf2 v = *(const vf2*)(Xb + (SRCOFF) + boff[k]);                  \
      aA += wA[k] * v;                                                       \
      aB += wB[k] * v;                                                       \
    }                                                                        \
    for (int e = spill0; e < eB1; ++e) {          /* ~never taken */         \
      const uint2 en = e2[e];                                                \
      const float w = __uint_as_float(en.x);                                 \
      const vf2 v = *(const vf2*)(Xb + (SRCOFF) + (int)(en.y * 8u));         \
      if (e < eA1) aA += w * v; else aB += w * v;                            \
    }                                                                        \
    yA = (vf2){mml_f(aA.x), mml_f(aA.y)};                                    \
    yB = (vf2){mml_f(aB.x), mml_f(aB.y)};                                    \
    *(float4*)(Xb + (DSTOFF) + wr) = make_float4(yA.x, yA.y, yB.x, yB.y);    \
    __syncthreads();                                                         \
  }

  STEP(0, BUF1);                                  // step 2
  for (int i = 0; i < (STEPS - 2) / 2; ++i) {     // 29 double-steps: 3..60
    STEP(BUF1, 0);
    STEP(0, BUF1);
  }
#undef STEP

  out[(size_t)s0 * NN + oldA]       = yA.x;
  out[(size_t)(s0 + 1) * NN + oldA] = yA.y;
  out[(size_t)s0 * NN + oldB]       = yB.x;
  out[(size_t)(s0 + 1) * NN + oldB] = yB.y;
}

extern "C" void kernel_launch(void* const* d_in, const int* in_sizes, int n_in,
                              void* d_out, int out_size, void* d_ws, size_t ws_size,
                              hipStream_t stream) {
  const float* Xfull = (const float*)d_in[0];   // (B, N) f32
  const float* W     = (const float*)d_in[1];   // (N, N) f32
  const float* bias  = (const float*)d_in[2];   // (N, 1) f32
  float* out = (float*)d_out;

  // ws: pg[EMAX]u2 | e2[EMAX]u2 | e3[EPT*1024]u2 | cnt[NN] | base[NN+1] |
  //     perm[NN] | newid[NN] | tb[1025] | tmid[1024] | pa[1024] | pb[1024]
  char* ws = (char*)d_ws;
  uint2* pg  = (uint2*)ws;                              ws += (size_t)EMAX * 8;
  uint2* e2  = (uint2*)ws;                              ws += (size_t)EMAX * 8;
  uint2* e3  = (uint2*)ws;                              ws += (size_t)EPT * 1024 * 8;
  int* cnt   = (int*)ws;                                ws += (size_t)NN * 4;
  int* base  = (int*)ws;                                ws += (size_t)(NN + 1) * 4;
  int* perm  = (int*)ws;                                ws += (size_t)NN * 4;
  int* newid = (int*)ws;                                ws += (size_t)NN * 4;
  int* tb    = (int*)ws;                                ws += (size_t)1025 * 4;
  int* tmid  = (int*)ws;                                ws += (size_t)1024 * 4;
  int* pa    = (int*)ws;                                ws += (size_t)1024 * 4;
  int* pb    = (int*)ws;

  const int B = in_sizes[0] / NN;   // 512

  hipMemsetAsync(pg, 0, (size_t)EMAX * 16, stream);   // pg + e2 tails defined
  count_row<<<NN, 64, 0, stream>>>(W, cnt);
  scan2048<<<1, 1024, 0, stream>>>(cnt, base);
  fill_edges<<<NN, 64, 0, stream>>>(W, base, pg);
  sortnodes<<<1, 1024, 0, stream>>>(cnt, perm);
  pair_layout<<<1, 1024, 0, stream>>>(cnt, base, pg, perm, e2, tb, tmid, pa, pb);
  renum<<<1, 1024, 0, stream>>>(pa, pb, newid);
  remap<<<EMAX / 256, 256, 0, stream>>>(e2, newid);
  sched<<<1, 16, 0, stream>>>(e2, tb, tmid, e3);
  sim<<<B / SPB, TPB, 0, stream>>>(Xfull, bias, e2, e3, tb, tmid, pa, pb, out);
}

// Round 16
// 174.351 us; speedup vs baseline: 20.2617x; 20.2617x over previous
//
#include <hip/hip_runtime.h>

// SignalingModel: X_{t+1} = mml(W @ X_t + X_bias), 60 steps, W 0.24% sparse.
// R13 = R12's sim (register edges, renumbered paired b128 stores, compile-time
// ping-pong) + O(1)-cost PARALLEL bank scheduler (R12's serial greedy was a
// 3.77ms build-stage disaster that buried the sim measurement):
//  - per-thread: sort own <=14 edges by bank-pair (src&15), slot k reads
//    rotated position (k + t%EPT) % EPT -> quantile stagger spreads banks in
//    each slot ~uniformly (max load ~4-5, same as greedy).
//  - dead slots replicate a real edge addr with w=0 (no bank-0 pile-up).
//  - one-time build kernel, scratch arrays fine; ~us.
// Lessons: price EVERY launched kernel, not just the hot one (R12); LDS
// effective cycles is the serial resource (R10/R11); register edges need
// compile-time indexing (R9); zigzag pairing for barrier balance (R8).

#define NN 2048
#define STEPS 60
#define LEAKV 0.01f
#define EMAX 10240
#define TPB 1024
#define SPB 2
#define NB 64
#define EPT 14
#define BUF1 16384        // byte offset of second state buffer (NN*8)

typedef float vf2 __attribute__((ext_vector_type(2)));

__device__ __forceinline__ float mml_f(float x) {
  if (x < 0.0f)      return LEAKV * x;
  else if (x < 0.5f) return x;
  else               return 1.0f - 0.25f / x;
}

// --- build pipeline -------------------------------------------------------

__global__ __launch_bounds__(64) void count_row(const float* __restrict__ W,
                                                int* __restrict__ cnt) {
  const int n = blockIdx.x, lane = threadIdx.x;
  int c = 0;
  for (int c0 = 0; c0 < NN; c0 += 64) {
    float w = W[n * NN + c0 + lane];
    c += __popcll(__ballot(w != 0.0f));
  }
  if (lane == 0) cnt[n] = c;
}

__global__ __launch_bounds__(1024) void scan2048(const int* __restrict__ cnt,
                                                 int* __restrict__ base) {
  __shared__ int sb[2][NN];
  const int t = threadIdx.x;
  sb[0][t] = cnt[t];
  sb[0][t + 1024] = cnt[t + 1024];
  __syncthreads();
  int p = 0;
  for (int off = 1; off < NN; off <<= 1) {
    int i0 = t, i1 = t + 1024;
    sb[p ^ 1][i0] = sb[p][i0] + (i0 >= off ? sb[p][i0 - off] : 0);
    sb[p ^ 1][i1] = sb[p][i1] + (i1 >= off ? sb[p][i1 - off] : 0);
    __syncthreads();
    p ^= 1;
  }
  base[t] = sb[p][t] - cnt[t];
  base[t + 1024] = sb[p][t + 1024] - cnt[t + 1024];
  if (t == 1023) base[NN] = sb[p][NN - 1];
}

__global__ __launch_bounds__(64) void fill_edges(const float* __restrict__ W,
                                                 const int* __restrict__ base,
                                                 uint2* __restrict__ pg) {
  const int n = blockIdx.x, lane = threadIdx.x;
  const int b = base[n];
  int off = 0;
  for (int c0 = 0; c0 < NN; c0 += 64) {
    float w = W[n * NN + c0 + lane];
    unsigned long long m = __ballot(w != 0.0f);
    if (w != 0.0f) {
      int e = b + off + __popcll(m & ((1ull << lane) - 1ull));
      pg[e] = make_uint2(__float_as_uint(w), (unsigned)(c0 + lane));
    }
    off += __popcll(m);
  }
}

// degree counting-sort: perm[rank]=node, ascending. Unstable within bucket --
// output-invariant (per-node edges keep their identity wherever they land).
__global__ __launch_bounds__(1024) void sortnodes(const int* __restrict__ cnt,
                                                  int* __restrict__ perm) {
  __shared__ int bases[NB];
  const int t = threadIdx.x;
  if (t < NB) bases[t] = 0;
  __syncthreads();
  int d0 = min(cnt[t], NB - 1);
  int d1 = min(cnt[t + 1024], NB - 1);
  atomicAdd(&bases[d0], 1);
  atomicAdd(&bases[d1], 1);
  __syncthreads();
  if (t == 0) {
    int acc = 0;
    for (int i = 0; i < NB; ++i) { int h = bases[i]; bases[i] = acc; acc += h; }
  }
  __syncthreads();
  perm[atomicAdd(&bases[d0], 1)] = t;
  perm[atomicAdd(&bases[d1], 1)] = t + 1024;
}

// zigzag pair + thread-contiguous edge re-layout (CSR order preserved).
__global__ __launch_bounds__(1024) void pair_layout(const int* __restrict__ cnt,
                                                    const int* __restrict__ base,
                                                    const uint2* __restrict__ pg,
                                                    const int* __restrict__ perm,
                                                    uint2* __restrict__ e2,
                                                    int* __restrict__ tb,
                                                    int* __restrict__ tmid,
                                                    int* __restrict__ pa,
                                                    int* __restrict__ pb) {
  __shared__ int sc[2][1024];
  const int t = threadIdx.x;
  const int nA = perm[t], nB = perm[2047 - t];
  const int dA = cnt[nA], dB = cnt[nB];
  sc[0][t] = dA + dB;
  __syncthreads();
  int p = 0;
  for (int off = 1; off < 1024; off <<= 1) {
    sc[p ^ 1][t] = sc[p][t] + (t >= off ? sc[p][t - off] : 0);
    __syncthreads();
    p ^= 1;
  }
  const int b = sc[p][t] - (dA + dB);
  tb[t] = b;
  tmid[t] = b + dA;
  pa[t] = nA;
  pb[t] = nB;
  if (t == 1023) tb[1024] = sc[p][t];
  const int bA = base[nA], bB = base[nB];
  for (int k = 0; k < dA; ++k) e2[b + k] = pg[bA + k];
  for (int k = 0; k < dB; ++k) e2[b + dA + k] = pg[bB + k];
}

// node renumbering: thread t's nodes become new-ids {2t, 2t+1}
__global__ __launch_bounds__(1024) void renum(const int* __restrict__ pa,
                                              const int* __restrict__ pb,
                                              int* __restrict__ newid) {
  const int t = threadIdx.x;
  newid[pa[t]] = 2 * t;
  newid[pb[t]] = 2 * t + 1;
}

__global__ __launch_bounds__(256) void remap(uint2* __restrict__ e2,
                                             const int* __restrict__ newid) {
  const int e = blockIdx.x * 256 + threadIdx.x;
  e2[e].y = (unsigned)newid[e2[e].y];
}

// PARALLEL bank scheduler: one thread per sim thread (one-time; scratch ok).
// Sort own edges by bank-pair (src&15); slot k = rotated sorted position
// (k + t%EPT) % EPT; positions >= deg replicate a real edge with w=0.
// e3[k*1024 + t] = (w_bits, (byte_off<<1)|isA).
__global__ __launch_bounds__(1024) void sched2(const uint2* __restrict__ e2,
                                               const int* __restrict__ tb,
                                               const int* __restrict__ tmid,
                                               uint2* __restrict__ e3) {
  const int t = threadIdx.x;
  const int b0 = tb[t], b1 = tb[t + 1], mid = tmid[t];
  int deg = b1 - b0; if (deg > EPT) deg = EPT;

  unsigned wb[EPT], mt[EPT];
  int bk[EPT];
  for (int i = 0; i < deg; ++i) {
    const uint2 en = e2[b0 + i];
    wb[i] = en.x;
    mt[i] = ((en.y * 8u) << 1) | (((b0 + i) < mid) ? 1u : 0u);
    bk[i] = (int)(en.y & 15u);
  }
  for (int i = 1; i < deg; ++i) {               // insertion sort by bank
    const unsigned w0 = wb[i], m0 = mt[i];
    const int k0 = bk[i];
    int j = i - 1;
    while (j >= 0 && bk[j] > k0) {
      wb[j + 1] = wb[j]; mt[j + 1] = mt[j]; bk[j + 1] = bk[j]; --j;
    }
    wb[j + 1] = w0; mt[j + 1] = m0; bk[j + 1] = k0;
  }
  const int r = t % EPT;                        // quantile stagger
  for (int k = 0; k < EPT; ++k) {
    const int p = (k + r) % EPT;
    uint2 o;
    if (deg == 0)        o = make_uint2(0u, 0u);
    else if (p < deg)    o = make_uint2(wb[p], mt[p]);
    else                 o = make_uint2(0u, mt[p % deg]);   // dup addr, w=0
    e3[k * 1024 + t] = o;
  }
}

// --- simulation (identical to R12) ----------------------------------------
__global__ __launch_bounds__(TPB, 4) void sim(const float* __restrict__ Xfull,
                                              const float* __restrict__ bias,
                                              const uint2* __restrict__ e2,
                                              const uint2* __restrict__ e3,
                                              const int* __restrict__ tb,
                                              const int* __restrict__ tmid,
                                              const int* __restrict__ pa,
                                              const int* __restrict__ pb,
                                              float* __restrict__ out) {
  __shared__ float2 X[2][NN];                     // 32 KB
  char* Xb = (char*)&X[0][0];
  const int t  = (int)threadIdx.x;
  const int s0 = (int)blockIdx.x * SPB;

  const int eA1 = tmid[t], eB1 = tb[t + 1];
  const int spill0 = tb[t] + EPT;
  const int oldA = pa[t], oldB = pb[t];

  float wA[EPT], wB[EPT];
  int boff[EPT];
#pragma unroll
  for (int k = 0; k < EPT; ++k) {
    const uint2 en = e3[k * 1024 + t];
    const float wv = __uint_as_float(en.x);
    const bool isA = (en.y & 1u) != 0u;
    wA[k] = isA ? wv : 0.0f;
    wB[k] = isA ? 0.0f : wv;
    boff[k] = (int)(en.y >> 1);
  }

  const vf2 xbA = {Xfull[(size_t)s0 * NN + oldA] + bias[oldA],
                   Xfull[(size_t)(s0 + 1) * NN + oldA] + bias[oldA]};
  const vf2 xbB = {Xfull[(size_t)s0 * NN + oldB] + bias[oldB],
                   Xfull[(size_t)(s0 + 1) * NN + oldB] + bias[oldB]};
  const int wr = t * 16;

  *(float4*)(Xb + wr) = make_float4(mml_f(xbA.x), mml_f(xbA.y),
                                    mml_f(xbB.x), mml_f(xbB.y));
  __syncthreads();

  vf2 yA, yB;

#define STEP(SRCOFF, DSTOFF)                                                 \
  {                                                                          \
    vf2 aA = xbA, aB = xbB;                                                  \
    _Pragma("unroll")                                                        \
    for (int k = 0; k < EPT; ++k) {                                          \
      const vf2 v = *(const vf2*)(Xb + (SRCOFF) + boff[k]);                  \
      aA += wA[k] * v;                                                       \
      aB += wB[k] * v;                                                       \
    }                                                                        \
    for (int e = spill0; e < eB1; ++e) {          /* ~never taken */         \
      const uint2 en = e2[e];                                                \
      const float w = __uint_as_float(en.x);                                 \
      const vf2 v = *(const vf2*)(Xb + (SRCOFF) + (int)(en.y * 8u));         \
      if (e < eA1) aA += w * v; else aB += w * v;                            \
    }                                                                        \
    yA = (vf2){mml_f(aA.x), mml_f(aA.y)};                                    \
    yB = (vf2){mml_f(aB.x), mml_f(aB.y)};                                    \
    *(float4*)(Xb + (DSTOFF) + wr) = make_float4(yA.x, yA.y, yB.x, yB.y);    \
    __syncthreads();                                                         \
  }

  STEP(0, BUF1);                                  // step 2
  for (int i = 0; i < (STEPS - 2) / 2; ++i) {     // 29 double-steps: 3..60
    STEP(BUF1, 0);
    STEP(0, BUF1);
  }
#undef STEP

  out[(size_t)s0 * NN + oldA]       = yA.x;
  out[(size_t)(s0 + 1) * NN + oldA] = yA.y;
  out[(size_t)s0 * NN + oldB]       = yB.x;
  out[(size_t)(s0 + 1) * NN + oldB] = yB.y;
}

extern "C" void kernel_launch(void* const* d_in, const int* in_sizes, int n_in,
                              void* d_out, int out_size, void* d_ws, size_t ws_size,
                              hipStream_t stream) {
  const float* Xfull = (const float*)d_in[0];   // (B, N) f32
  const float* W     = (const float*)d_in[1];   // (N, N) f32
  const float* bias  = (const float*)d_in[2];   // (N, 1) f32
  float* out = (float*)d_out;

  // ws: pg[EMAX]u2 | e2[EMAX]u2 | e3[EPT*1024]u2 | cnt[NN] | base[NN+1] |
  //     perm[NN] | newid[NN] | tb[1025] | tmid[1024] | pa[1024] | pb[1024]
  char* ws = (char*)d_ws;
  uint2* pg  = (uint2*)ws;                              ws += (size_t)EMAX * 8;
  uint2* e2  = (uint2*)ws;                              ws += (size_t)EMAX * 8;
  uint2* e3  = (uint2*)ws;                              ws += (size_t)EPT * 1024 * 8;
  int* cnt   = (int*)ws;                                ws += (size_t)NN * 4;
  int* base  = (int*)ws;                                ws += (size_t)(NN + 1) * 4;
  int* perm  = (int*)ws;                                ws += (size_t)NN * 4;
  int* newid = (int*)ws;                                ws += (size_t)NN * 4;
  int* tb    = (int*)ws;                                ws += (size_t)1025 * 4;
  int* tmid  = (int*)ws;                                ws += (size_t)1024 * 4;
  int* pa    = (int*)ws;                                ws += (size_t)1024 * 4;
  int* pb    = (int*)ws;

  const int B = in_sizes[0] / NN;   // 512

  hipMemsetAsync(pg, 0, (size_t)EMAX * 16, stream);   // pg + e2 tails defined
  count_row<<<NN, 64, 0, stream>>>(W, cnt);
  scan2048<<<1, 1024, 0, stream>>>(cnt, base);
  fill_edges<<<NN, 64, 0, stream>>>(W, base, pg);
  sortnodes<<<1, 1024, 0, stream>>>(cnt, perm);
  pair_layout<<<1, 1024, 0, stream>>>(cnt, base, pg, perm, e2, tb, tmid, pa, pb);
  renum<<<1, 1024, 0, stream>>>(pa, pb, newid);
  remap<<<EMAX / 256, 256, 0, stream>>>(e2, newid);
  sched2<<<1, 1024, 0, stream>>>(e2, tb, tmid, e3);
  sim<<<B / SPB, TPB, 0, stream>>>(Xfull, bias, e2, e3, tb, tmid, pa, pb, out);
}

// Round 17
// 149.165 us; speedup vs baseline: 23.6828x; 1.1688x over previous
//
#include <hip/hip_runtime.h>

// SignalingModel: X_{t+1} = mml(W @ X_t + X_bias), 60 steps, W 0.24% sparse.
// R14 = R11/R13 sim + ballot-coordinated greedy bank scheduler (bsched).
//  - R13 lesson: per-lane rotation CORRELATED banks (sorted quantiles) ->
//    conflicts up. Balancing needs cross-lane coordination.
//  - bsched: 1 wave per sim-wave (16 blocks x 64), per slot: 3 rounds of
//    {propose min-load bank-pair, rank via 16 ballots, accept if load+rank<5
//    (last round forced), LDS-atomic update}. Dead lanes broadcast an
//    assigned lane's addr with w=0 (same-addr = free). Register-resident,
//    compile-time indexed (no scratch - R12/R13 lesson).
// Lessons: LDS effective cycles is the serial resource; conflicts ~22% of
// step (R11); occupancy structurally capped at 16 waves/CU (R9/R10); price
// every build kernel (R12).

#define NN 2048
#define STEPS 60
#define LEAKV 0.01f
#define EMAX 10240
#define TPB 1024
#define SPB 2
#define NB 64
#define EPT 14
#define BUF1 16384        // byte offset of second state buffer (NN*8)

typedef float vf2 __attribute__((ext_vector_type(2)));

__device__ __forceinline__ float mml_f(float x) {
  if (x < 0.0f)      return LEAKV * x;
  else if (x < 0.5f) return x;
  else               return 1.0f - 0.25f / x;
}

// --- build pipeline -------------------------------------------------------

__global__ __launch_bounds__(64) void count_row(const float* __restrict__ W,
                                                int* __restrict__ cnt) {
  const int n = blockIdx.x, lane = threadIdx.x;
  int c = 0;
  for (int c0 = 0; c0 < NN; c0 += 64) {
    float w = W[n * NN + c0 + lane];
    c += __popcll(__ballot(w != 0.0f));
  }
  if (lane == 0) cnt[n] = c;
}

__global__ __launch_bounds__(1024) void scan2048(const int* __restrict__ cnt,
                                                 int* __restrict__ base) {
  __shared__ int sb[2][NN];
  const int t = threadIdx.x;
  sb[0][t] = cnt[t];
  sb[0][t + 1024] = cnt[t + 1024];
  __syncthreads();
  int p = 0;
  for (int off = 1; off < NN; off <<= 1) {
    int i0 = t, i1 = t + 1024;
    sb[p ^ 1][i0] = sb[p][i0] + (i0 >= off ? sb[p][i0 - off] : 0);
    sb[p ^ 1][i1] = sb[p][i1] + (i1 >= off ? sb[p][i1 - off] : 0);
    __syncthreads();
    p ^= 1;
  }
  base[t] = sb[p][t] - cnt[t];
  base[t + 1024] = sb[p][t + 1024] - cnt[t + 1024];
  if (t == 1023) base[NN] = sb[p][NN - 1];
}

__global__ __launch_bounds__(64) void fill_edges(const float* __restrict__ W,
                                                 const int* __restrict__ base,
                                                 uint2* __restrict__ pg) {
  const int n = blockIdx.x, lane = threadIdx.x;
  const int b = base[n];
  int off = 0;
  for (int c0 = 0; c0 < NN; c0 += 64) {
    float w = W[n * NN + c0 + lane];
    unsigned long long m = __ballot(w != 0.0f);
    if (w != 0.0f) {
      int e = b + off + __popcll(m & ((1ull << lane) - 1ull));
      pg[e] = make_uint2(__float_as_uint(w), (unsigned)(c0 + lane));
    }
    off += __popcll(m);
  }
}

// degree counting-sort: perm[rank]=node, ascending. Unstable within bucket --
// output-invariant (per-node edges keep their identity wherever they land).
__global__ __launch_bounds__(1024) void sortnodes(const int* __restrict__ cnt,
                                                  int* __restrict__ perm) {
  __shared__ int bases[NB];
  const int t = threadIdx.x;
  if (t < NB) bases[t] = 0;
  __syncthreads();
  int d0 = min(cnt[t], NB - 1);
  int d1 = min(cnt[t + 1024], NB - 1);
  atomicAdd(&bases[d0], 1);
  atomicAdd(&bases[d1], 1);
  __syncthreads();
  if (t == 0) {
    int acc = 0;
    for (int i = 0; i < NB; ++i) { int h = bases[i]; bases[i] = acc; acc += h; }
  }
  __syncthreads();
  perm[atomicAdd(&bases[d0], 1)] = t;
  perm[atomicAdd(&bases[d1], 1)] = t + 1024;
}

// zigzag pair + thread-contiguous edge re-layout (CSR order preserved).
__global__ __launch_bounds__(1024) void pair_layout(const int* __restrict__ cnt,
                                                    const int* __restrict__ base,
                                                    const uint2* __restrict__ pg,
                                                    const int* __restrict__ perm,
                                                    uint2* __restrict__ e2,
                                                    int* __restrict__ tb,
                                                    int* __restrict__ tmid,
                                                    int* __restrict__ pa,
                                                    int* __restrict__ pb) {
  __shared__ int sc[2][1024];
  const int t = threadIdx.x;
  const int nA = perm[t], nB = perm[2047 - t];
  const int dA = cnt[nA], dB = cnt[nB];
  sc[0][t] = dA + dB;
  __syncthreads();
  int p = 0;
  for (int off = 1; off < 1024; off <<= 1) {
    sc[p ^ 1][t] = sc[p][t] + (t >= off ? sc[p][t - off] : 0);
    __syncthreads();
    p ^= 1;
  }
  const int b = sc[p][t] - (dA + dB);
  tb[t] = b;
  tmid[t] = b + dA;
  pa[t] = nA;
  pb[t] = nB;
  if (t == 1023) tb[1024] = sc[p][t];
  const int bA = base[nA], bB = base[nB];
  for (int k = 0; k < dA; ++k) e2[b + k] = pg[bA + k];
  for (int k = 0; k < dB; ++k) e2[b + dA + k] = pg[bB + k];
}

// node renumbering: thread t's nodes become new-ids {2t, 2t+1}
__global__ __launch_bounds__(1024) void renum(const int* __restrict__ pa,
                                              const int* __restrict__ pb,
                                              int* __restrict__ newid) {
  const int t = threadIdx.x;
  newid[pa[t]] = 2 * t;
  newid[pb[t]] = 2 * t + 1;
}

__global__ __launch_bounds__(256) void remap(uint2* __restrict__ e2,
                                             const int* __restrict__ newid) {
  const int e = blockIdx.x * 256 + threadIdx.x;
  e2[e].y = (unsigned)newid[e2[e].y];
}

// ballot-coordinated greedy bank scheduler: one wave per sim-wave.
// Per slot k: fresh load[16]; 3 rounds {propose min-load bank-pair among own
// unused edges; rank via 16 ballots; accept if load+rank<5 (round 2 forced);
// atomic load update}. Dead lanes: broadcast first assigned lane's addr, w=0.
// e3[k*1024+t] = (w_bits, (byte_off<<1)|isA). Deterministic.
__global__ __launch_bounds__(64) void bsched(const uint2* __restrict__ e2,
                                             const int* __restrict__ tb,
                                             const int* __restrict__ tmid,
                                             uint2* __restrict__ e3) {
  const int w = blockIdx.x, l = threadIdx.x, t = w * 64 + l;
  __shared__ int load[16];
  __shared__ unsigned bcast;
  const unsigned long long ltmask =
      (l == 63) ? 0x7fffffffffffffffull : ((1ull << l) - 1ull);
  const int b0 = tb[t], b1 = tb[t + 1], mid = tmid[t];
  const int deg = min(b1 - b0, EPT);

  unsigned wv[EPT], mv[EPT];
  int bp[EPT];
#pragma unroll
  for (int i = 0; i < EPT; ++i) {
    const bool v = i < deg;
    const uint2 en = e2[b0 + (v ? i : 0)];
    wv[i] = v ? en.x : 0u;
    mv[i] = ((en.y * 8u) << 1) | ((v && (b0 + i) < mid) ? 1u : 0u);
    bp[i] = (int)(en.y & 15u);
  }
  unsigned used = 0;

  for (int k = 0; k < EPT; ++k) {
    if (l < 16) load[l] = 0;
    if (l == 0) bcast = 0;
    __syncthreads();
    bool assigned = false;
    unsigned cw = 0, cm = 0;
    for (int round = 0; round < 3; ++round) {
      int myb = -1, myld = 1 << 29, mye = -1;
      if (!assigned) {
#pragma unroll
        for (int i = 0; i < EPT; ++i) {
          if (i < deg && !((used >> i) & 1u)) {
            const int li = load[bp[i]];
            if (li < myld) { myld = li; myb = bp[i]; mye = i; }
          }
        }
      }
      int rank = 0;
#pragma unroll
      for (int b = 0; b < 16; ++b) {
        const unsigned long long mb = __ballot(myb == b);
        if (myb == b) rank = (int)__popcll(mb & ltmask);
      }
      const bool acc = (myb >= 0) && (round == 2 || (myld + rank) < 5);
      if (acc) {
        assigned = true;
        used |= (1u << mye);
#pragma unroll
        for (int i = 0; i < EPT; ++i) if (i == mye) { cw = wv[i]; cm = mv[i]; }
        atomicAdd(&load[myb], 1);
      }
      __syncthreads();
    }
    const unsigned long long am = __ballot(assigned);
    if (assigned && l == (int)(__ffsll((long long)am) - 1)) bcast = cm & ~1u;
    __syncthreads();
    e3[k * 1024 + t] = assigned ? make_uint2(cw, cm) : make_uint2(0u, bcast);
    __syncthreads();
  }
}

// --- simulation (identical to R13) ----------------------------------------
__global__ __launch_bounds__(TPB, 4) void sim(const float* __restrict__ Xfull,
                                              const float* __restrict__ bias,
                                              const uint2* __restrict__ e2,
                                              const uint2* __restrict__ e3,
                                              const int* __restrict__ tb,
                                              const int* __restrict__ tmid,
                                              const int* __restrict__ pa,
                                              const int* __restrict__ pb,
                                              float* __restrict__ out) {
  __shared__ float2 X[2][NN];                     // 32 KB
  char* Xb = (char*)&X[0][0];
  const int t  = (int)threadIdx.x;
  const int s0 = (int)blockIdx.x * SPB;

  const int eA1 = tmid[t], eB1 = tb[t + 1];
  const int spill0 = tb[t] + EPT;
  const int oldA = pa[t], oldB = pb[t];

  float wA[EPT], wB[EPT];
  int boff[EPT];
#pragma unroll
  for (int k = 0; k < EPT; ++k) {
    const uint2 en = e3[k * 1024 + t];
    const float wv = __uint_as_float(en.x);
    const bool isA = (en.y & 1u) != 0u;
    wA[k] = isA ? wv : 0.0f;
    wB[k] = isA ? 0.0f : wv;
    boff[k] = (int)(en.y >> 1);
  }

  const vf2 xbA = {Xfull[(size_t)s0 * NN + oldA] + bias[oldA],
                   Xfull[(size_t)(s0 + 1) * NN + oldA] + bias[oldA]};
  const vf2 xbB = {Xfull[(size_t)s0 * NN + oldB] + bias[oldB],
                   Xfull[(size_t)(s0 + 1) * NN + oldB] + bias[oldB]};
  const int wr = t * 16;

  *(float4*)(Xb + wr) = make_float4(mml_f(xbA.x), mml_f(xbA.y),
                                    mml_f(xbB.x), mml_f(xbB.y));
  __syncthreads();

  vf2 yA, yB;

#define STEP(SRCOFF, DSTOFF)                                                 \
  {                                                                          \
    vf2 aA = xbA, aB = xbB;                                                  \
    _Pragma("unroll")                                                        \
    for (int k = 0; k < EPT; ++k) {                                          \
      const vf2 v = *(const vf2*)(Xb + (SRCOFF) + boff[k]);                  \
      aA += wA[k] * v;                                                       \
      aB += wB[k] * v;                                                       \
    }                                                                        \
    for (int e = spill0; e < eB1; ++e) {          /* ~never taken */         \
      const uint2 en = e2[e];                                                \
      const float w = __uint_as_float(en.x);                                 \
      const vf2 v = *(const vf2*)(Xb + (SRCOFF) + (int)(en.y * 8u));         \
      if (e < eA1) aA += w * v; else aB += w * v;                            \
    }                                                                        \
    yA = (vf2){mml_f(aA.x), mml_f(aA.y)};                                    \
    yB = (vf2){mml_f(aB.x), mml_f(aB.y)};                                    \
    *(float4*)(Xb + (DSTOFF) + wr) = make_float4(yA.x, yA.y, yB.x, yB.y);    \
    __syncthreads();                                                         \
  }

  STEP(0, BUF1);                                  // step 2
  for (int i = 0; i < (STEPS - 2) / 2; ++i) {     // 29 double-steps: 3..60
    STEP(BUF1, 0);
    STEP(0, BUF1);
  }
#undef STEP

  out[(size_t)s0 * NN + oldA]       = yA.x;
  out[(size_t)(s0 + 1) * NN + oldA] = yA.y;
  out[(size_t)s0 * NN + oldB]       = yB.x;
  out[(size_t)(s0 + 1) * NN + oldB] = yB.y;
}

extern "C" void kernel_launch(void* const* d_in, const int* in_sizes, int n_in,
                              void* d_out, int out_size, void* d_ws, size_t ws_size,
                              hipStream_t stream) {
  const float* Xfull = (const float*)d_in[0];   // (B, N) f32
  const float* W     = (const float*)d_in[1];   // (N, N) f32
  const float* bias  = (const float*)d_in[2];   // (N, 1) f32
  float* out = (float*)d_out;

  // ws: pg[EMAX]u2 | e2[EMAX]u2 | e3[EPT*1024]u2 | cnt[NN] | base[NN+1] |
  //     perm[NN] | newid[NN] | tb[1025] | tmid[1024] | pa[1024] | pb[1024]
  char* ws = (char*)d_ws;
  uint2* pg  = (uint2*)ws;                              ws += (size_t)EMAX * 8;
  uint2* e2  = (uint2*)ws;                              ws += (size_t)EMAX * 8;
  uint2* e3  = (uint2*)ws;                              ws += (size_t)EPT * 1024 * 8;
  int* cnt   = (int*)ws;                                ws += (size_t)NN * 4;
  int* base  = (int*)ws;                                ws += (size_t)(NN + 1) * 4;
  int* perm  = (int*)ws;                                ws += (size_t)NN * 4;
  int* newid = (int*)ws;                                ws += (size_t)NN * 4;
  int* tb    = (int*)ws;                                ws += (size_t)1025 * 4;
  int* tmid  = (int*)ws;                                ws += (size_t)1024 * 4;
  int* pa    = (int*)ws;                                ws += (size_t)1024 * 4;
  int* pb    = (int*)ws;

  const int B = in_sizes[0] / NN;   // 512

  hipMemsetAsync(pg, 0, (size_t)EMAX * 16, stream);   // pg + e2 tails defined
  count_row<<<NN, 64, 0, stream>>>(W, cnt);
  scan2048<<<1, 1024, 0, stream>>>(cnt, base);
  fill_edges<<<NN, 64, 0, stream>>>(W, base, pg);
  sortnodes<<<1, 1024, 0, stream>>>(cnt, perm);
  pair_layout<<<1, 1024, 0, stream>>>(cnt, base, pg, perm, e2, tb, tmid, pa, pb);
  renum<<<1, 1024, 0, stream>>>(pa, pb, newid);
  remap<<<EMAX / 256, 256, 0, stream>>>(e2, newid);
  bsched<<<16, 64, 0, stream>>>(e2, tb, tmid, e3);
  sim<<<B / SPB, TPB, 0, stream>>>(Xfull, bias, e2, e3, tb, tmid, pa, pb, out);
}